// Round 5
// baseline (146.429 us; speedup 1.0000x reference)
//
#include <hip/hip_runtime.h>

#define LOG2E 1.4426950408889634f
#define LN2 0.6931471805599453f

constexpr int Ee = 768;
constexpr int BN = 512;
// ws layout (floats). Overlays (all safe by in-stream ordering):
//   P  (qkv partials, 2x1179648)  at 1179648  -- dead after k_qkvreduce
//   kmT [768][512]                at 1179648  -- written after P dies
//   PVP (PV partials, 2x393216)   at 0        -- over dead q/keysT
//   PJP (proj partials, 2x393216) at 1179648  -- over dead kmT (+EN head)
// High-water = 3538944 floats = 14.2 MB.
constexpr long QC_OFF = 0;              // q       [512][768]
constexpr long KT_OFF = 393216;         // keysT   [768][512]
constexpr long VC_OFF = 786432;         // v       [512][768]
constexpr long P_OFF  = 1179648;        // qkv partials [2][512][2304]
constexpr long PSTRIDE = 1179648;
constexpr long KM_OFF = 1179648;        // kmT     [768][512]
constexpr long EN_OFF = 1572864;        // energy  [24][256][256]
constexpr long PVP_OFF = 0;             // PV partials [2][512][768]
constexpr long PJP_OFF = 1179648;       // proj partials [2][512][768]
constexpr long PART = 393216;

// ---------------- fp32 tiled GEMM, 32x64 tile, KT=16, 128 thr, 4x4 micro ---
// C[row][col] = sum_k A[row][k]*B[k][col]
// KS: K-split parts (partial at C + kp*sCp, caller reduces).
// AR==2: A element = A[idx] + A[idx + sAp] (fold a previous K-split reduce).
template<int AR>
__global__ __launch_bounds__(128)
void gemm_k(const float* __restrict__ A, int lda, long sAb, long sAh, long sAp,
            const float* __restrict__ Bm, int ldb, long sBb, long sBh,
            float* __restrict__ C, int ldc, long sCb, long sCh, long sCp,
            const float* __restrict__ bias, int K, int Hdiv, int KS)
{
    __shared__ __align__(16) float As[16][36];
    __shared__ __align__(16) float Bs[16][68];
    const int tid = threadIdx.x;
    const int tx = tid & 15, ty = tid >> 4;
    const int m0 = blockIdx.x * 32, n0 = blockIdx.y * 64;
    const int kp = blockIdx.z % KS;
    const int zz = blockIdx.z / KS;
    const int zb = zz / Hdiv, zh = zz - zb * Hdiv;
    A  += zb * sAb + zh * sAh + (long)kp * K;
    Bm += zb * sBb + zh * sBh + (long)kp * K * ldb;
    C  += zb * sCb + zh * sCh + (long)kp * sCp;
    const int ar = tid >> 2, ac = (tid & 3) * 4;    // A: 32 rows x 16 k
    const int br = tid >> 4, bc = (tid & 15) * 4;   // B: 16 k x 64 n
    float acc[4][4] = {};

    const float* ap = &A[(long)(m0 + ar) * lda + ac];
    float4 av = *(const float4*)ap;
    if (AR == 2) {
        const float4 w = *(const float4*)(ap + sAp);
        av.x += w.x; av.y += w.y; av.z += w.z; av.w += w.w;
    }
    float4 bv0 = *(const float4*)&Bm[(long)(br + 0) * ldb + (n0 + bc)];
    float4 bv1 = *(const float4*)&Bm[(long)(br + 8) * ldb + (n0 + bc)];

    for (int k0 = 0; k0 < K; k0 += 16) {
        __syncthreads();
        As[ac + 0][ar] = av.x; As[ac + 1][ar] = av.y;
        As[ac + 2][ar] = av.z; As[ac + 3][ar] = av.w;
        *(float4*)&Bs[br + 0][bc] = bv0;
        *(float4*)&Bs[br + 8][bc] = bv1;
        __syncthreads();
        if (k0 + 16 < K) {   // next-tile loads overlap compute below
            const float* a2 = &A[(long)(m0 + ar) * lda + (k0 + 16 + ac)];
            av = *(const float4*)a2;
            if (AR == 2) {
                const float4 w = *(const float4*)(a2 + sAp);
                av.x += w.x; av.y += w.y; av.z += w.z; av.w += w.w;
            }
            bv0 = *(const float4*)&Bm[(long)(k0 + 16 + br + 0) * ldb + (n0 + bc)];
            bv1 = *(const float4*)&Bm[(long)(k0 + 16 + br + 8) * ldb + (n0 + bc)];
        }
        #pragma unroll
        for (int kk = 0; kk < 16; ++kk) {
            const float4 a = *(const float4*)&As[kk][ty * 4];
            const float4 b = *(const float4*)&Bs[kk][tx * 4];
            const float aa[4] = {a.x, a.y, a.z, a.w};
            const float bb[4] = {b.x, b.y, b.z, b.w};
            #pragma unroll
            for (int im = 0; im < 4; ++im)
                #pragma unroll
                for (int in = 0; in < 4; ++in)
                    acc[im][in] = fmaf(aa[im], bb[in], acc[im][in]);
        }
    }
    #pragma unroll
    for (int im = 0; im < 4; ++im) {
        const int row = m0 + ty * 4 + im;
        float4 v;
        float* vp = &v.x;
        #pragma unroll
        for (int in = 0; in < 4; ++in) {
            float x = acc[im][in];
            if (bias) x += bias[n0 + tx * 4 + in];
            vp[in] = x;
        }
        *(float4*)&C[(long)row * ldc + (n0 + tx * 4)] = v;
    }
}

// ------------- qkv K-split reduce + bias + scatter to q/keysT/v ------------
__global__ __launch_bounds__(256)
void k_qkvreduce(const float* __restrict__ P, const float* __restrict__ bias,
                 float* __restrict__ q, float* __restrict__ kT,
                 float* __restrict__ v)
{
    const int t = blockIdx.x * 256 + threadIdx.x;      // float4 id, 294912 total
    const int row = t / 576;
    const int c4 = (t - row * 576) * 4;
    const float4 p0 = *(const float4*)&P[(long)row * 2304 + c4];
    const float4 p1 = *(const float4*)&P[PSTRIDE + (long)row * 2304 + c4];
    const float4 bb = *(const float4*)&bias[c4];
    const float r[4] = {p0.x + p1.x + bb.x, p0.y + p1.y + bb.y,
                        p0.z + p1.z + bb.z, p0.w + p1.w + bb.w};
    #pragma unroll
    for (int e = 0; e < 4; ++e) {
        const int col = c4 + e;
        const int i = col / 3, s = col - i * 3;
        if (s == 0)      q [(long)row * Ee + i]  = r[e];
        else if (s == 1) kT[(long)i * BN + row]  = r[e];
        else             v [(long)row * Ee + i]  = r[e];
    }
}

// ---------------- Gaussian-mixture logsumexp (R=4 rows/thread) -------------
// block = one i, 128 threads; each thread owns 4 rows -> coefficient LDS
// reads amortized 4x. Wave-uniform coeff broadcast (conflict-free).
// Mix log-softmax normalizer + 0.5*log(2pi) dropped (uniform shift ->
// softmax-invariant). No max pass (t <= ~8 base-2; no overflow possible).
__global__ __launch_bounds__(128)
void k_mixture(const float* __restrict__ mean, const float* __restrict__ logvar,
               const float* __restrict__ mix, const float* __restrict__ keysT,
               float* __restrict__ kmT)
{
    __shared__ float aS[768], bS[768], cS[768];
    const int i = blockIdx.x;
    const int tid = threadIdx.x;

    #pragma unroll
    for (int r = 0; r < 6; ++r) {
        const int j = tid + r * 128;
        const float lv = logvar[i * Ee + j];
        const float mu = mean[i * Ee + j];
        const float istd2 = __builtin_amdgcn_exp2f(-lv * LOG2E);
        aS[j] = -0.5f * LOG2E * istd2;
        bS[j] = LOG2E * mu * istd2;
        cS[j] = fmaf(-0.5f * LOG2E * mu * mu, istd2, LOG2E * (mix[j] - 0.5f * lv));
    }
    __syncthreads();

    float kv[4], k2[4], s[4];
    #pragma unroll
    for (int r = 0; r < 4; ++r) {
        kv[r] = keysT[(long)i * BN + r * 128 + tid];
        k2[r] = kv[r] * kv[r];
        s[r] = 0.f;
    }
    const float4* a4 = (const float4*)aS;
    const float4* b4 = (const float4*)bS;
    const float4* c4 = (const float4*)cS;
    #pragma unroll 2
    for (int j4 = 0; j4 < 192; ++j4) {
        const float4 a = a4[j4], b = b4[j4], c = c4[j4];
        #pragma unroll
        for (int r = 0; r < 4; ++r) {
            s[r] += __builtin_amdgcn_exp2f(fmaf(a.x, k2[r], fmaf(b.x, kv[r], c.x)));
            s[r] += __builtin_amdgcn_exp2f(fmaf(a.y, k2[r], fmaf(b.y, kv[r], c.y)));
            s[r] += __builtin_amdgcn_exp2f(fmaf(a.z, k2[r], fmaf(b.z, kv[r], c.z)));
            s[r] += __builtin_amdgcn_exp2f(fmaf(a.w, k2[r], fmaf(b.w, kv[r], c.w)));
        }
    }
    #pragma unroll
    for (int r = 0; r < 4; ++r)
        kmT[(long)i * BN + r * 128 + tid] = LN2 * __builtin_amdgcn_logf(s[r]);
}

// ---------------- row softmax (in-place) with /sqrt(768) folded ------------
__global__ __launch_bounds__(256)
void k_softmax(float* __restrict__ e)
{
    const int row = blockIdx.x * 4 + (threadIdx.x >> 6);
    const int lane = threadIdx.x & 63;
    float4* p = (float4*)(e + (long)row * 256);
    float4 v = p[lane];
    float m = fmaxf(fmaxf(v.x, v.y), fmaxf(v.z, v.w));
    #pragma unroll
    for (int off = 32; off; off >>= 1) m = fmaxf(m, __shfl_xor(m, off, 64));
    v.x = __builtin_amdgcn_exp2f((v.x - m) * LOG2E);
    v.y = __builtin_amdgcn_exp2f((v.y - m) * LOG2E);
    v.z = __builtin_amdgcn_exp2f((v.z - m) * LOG2E);
    v.w = __builtin_amdgcn_exp2f((v.w - m) * LOG2E);
    float s = v.x + v.y + v.z + v.w;
    #pragma unroll
    for (int off = 32; off; off >>= 1) s += __shfl_xor(s, off, 64);
    const float sc = 1.0f / (s * 27.712812921102035f);  // * sqrt(768)
    v.x *= sc; v.y *= sc; v.z *= sc; v.w *= sc;
    p[lane] = v;
}

// ---------------- out = PJP0 + PJP1 + bias ------------
__global__ __launch_bounds__(256)
void k_outbias(const float* __restrict__ PJ, const float* __restrict__ bias,
               float* __restrict__ out)
{
    const int t = blockIdx.x * 256 + threadIdx.x;      // float4 id, 98304 total
    const int row = t / 192;
    const int c4 = (t - row * 192) * 4;
    const float4 p0 = *(const float4*)&PJ[(long)row * 768 + c4];
    const float4 p1 = *(const float4*)&PJ[PART + (long)row * 768 + c4];
    const float4 bb = *(const float4*)&bias[c4];
    float4 v = {p0.x + p1.x + bb.x, p0.y + p1.y + bb.y,
                p0.z + p1.z + bb.z, p0.w + p1.w + bb.w};
    *(float4*)&out[(long)row * 768 + c4] = v;
}

extern "C" void kernel_launch(void* const* d_in, const int* in_sizes, int n_in,
                              void* d_out, int out_size, void* d_ws, size_t ws_size,
                              hipStream_t stream)
{
    (void)in_sizes; (void)n_in; (void)out_size; (void)ws_size;
    const float* x      = (const float*)d_in[0];
    const float* Wqkv   = (const float*)d_in[1];
    const float* bqkv   = (const float*)d_in[2];
    const float* Wproj  = (const float*)d_in[3];
    const float* bproj  = (const float*)d_in[4];
    const float* mean   = (const float*)d_in[5];
    const float* logvar = (const float*)d_in[6];
    const float* mixc   = (const float*)d_in[7];
    float* out = (float*)d_out;
    float* ws = (float*)d_ws;
    float* qc     = ws + QC_OFF;
    float* keysT  = ws + KT_OFF;
    float* vc     = ws + VC_OFF;
    float* P      = ws + P_OFF;
    float* kmT    = ws + KM_OFF;
    float* energy = ws + EN_OFF;
    float* pvp    = ws + PVP_OFF;
    float* pjp    = ws + PJP_OFF;

    // 1a) qkv partials: x @ Wqkv, K split x2 (2304 waves)
    gemm_k<1><<<dim3(16,36,2),128,0,stream>>>(
        x,768,0,0,0, Wqkv,2304,0,0, P,2304,0,0,PSTRIDE,
        nullptr, 384, 1, 2);
    // 1b) reduce + bias + scatter to q / keysT / v
    k_qkvreduce<<<1152,256,0,stream>>>(P, bqkv, qc, keysT, vc);
    // 2) key_mix (transposed output kmT[i][row])
    k_mixture<<<768,128,0,stream>>>(mean, logvar, mixc, keysT, kmT);
    // 3) energy[b,h,q,k] = sum_d q[.,d] * kmT[d][k]  (1536 waves)
    gemm_k<1><<<dim3(8,4,24),128,0,stream>>>(
        qc,768,196608,64,0, kmT,512,256,32768, energy,256,786432,65536,0,
        nullptr, 64, 12, 1);
    // 4) att = softmax(energy)/sqrt(768), in place
    k_softmax<<<1536,256,0,stream>>>(energy);
    // 5) PV partials: att @ v, K split x2 (768 waves) -> pvp over dead q/keysT
    gemm_k<1><<<dim3(8,1,48),128,0,stream>>>(
        energy,256,786432,65536,0, vc,768,196608,64, pvp,768,196608,64,PART,
        nullptr, 128, 12, 2);
    // 6) proj partials: (pvp0+pvp1) @ Wproj, K split x2 (768 waves)
    gemm_k<2><<<dim3(16,12,2),128,0,stream>>>(
        pvp,768,0,0,PART, Wproj,768,0,0, pjp,768,0,0,PART,
        nullptr, 384, 1, 2);
    // 7) out = pjp0 + pjp1 + bproj
    k_outbias<<<384,256,0,stream>>>(pjp, bproj, out);
}

// Round 6
// 131.431 us; speedup vs baseline: 1.1141x; 1.1141x over previous
//
#include <hip/hip_runtime.h>

#define LOG2E 1.4426950408889634f
#define LN2 0.6931471805599453f

constexpr int Ee = 768;
constexpr int BN = 512;
// ws layout (floats). Overlays (all safe by in-stream ordering):
//   P  (qkv partials, 2x1179648)  at 1179648  -- dead after k_qkvreduce
//   kmT [768][512]                at 1179648  -- written after P dies
//   PVP (PV partials, 2x393216)   at 0        -- over dead q/keysT
//   PJP (proj partials, 2x393216) at 1179648  -- over dead kmT (+EN head)
// High-water = 3538944 floats = 14.2 MB.
constexpr long QC_OFF = 0;              // q       [512][768]
constexpr long KT_OFF = 393216;         // keysT   [768][512]
constexpr long VC_OFF = 786432;         // v       [512][768]
constexpr long P_OFF  = 1179648;        // qkv partials [2][512][2304]
constexpr long PSTRIDE = 1179648;
constexpr long KM_OFF = 1179648;        // kmT     [768][512]
constexpr long EN_OFF = 1572864;        // energy  [24][256][256]
constexpr long PVP_OFF = 0;             // PV partials [2][512][768]
constexpr long PJP_OFF = 1179648;       // proj partials [2][512][768]
constexpr long PART = 393216;

// ---------------- fp32 tiled GEMM, 32x64 tile, KT=16, 128 thr, 4x4 micro ---
// C[row][col] = sum_k A[row][k]*B[k][col]
// KS: K-split parts (partial at C + kp*sCp, caller reduces).
// AR==2: A element = A[idx] + A[idx + sAp] (fold a previous K-split reduce).
template<int AR>
__global__ __launch_bounds__(128)
void gemm_k(const float* __restrict__ A, int lda, long sAb, long sAh, long sAp,
            const float* __restrict__ Bm, int ldb, long sBb, long sBh,
            float* __restrict__ C, int ldc, long sCb, long sCh, long sCp,
            const float* __restrict__ bias, int K, int Hdiv, int KS)
{
    __shared__ __align__(16) float As[16][36];
    __shared__ __align__(16) float Bs[16][68];
    const int tid = threadIdx.x;
    const int tx = tid & 15, ty = tid >> 4;
    const int m0 = blockIdx.x * 32, n0 = blockIdx.y * 64;
    const int kp = blockIdx.z % KS;
    const int zz = blockIdx.z / KS;
    const int zb = zz / Hdiv, zh = zz - zb * Hdiv;
    A  += zb * sAb + zh * sAh + (long)kp * K;
    Bm += zb * sBb + zh * sBh + (long)kp * K * ldb;
    C  += zb * sCb + zh * sCh + (long)kp * sCp;
    const int ar = tid >> 2, ac = (tid & 3) * 4;    // A: 32 rows x 16 k
    const int br = tid >> 4, bc = (tid & 15) * 4;   // B: 16 k x 64 n
    float acc[4][4] = {};

    const float* ap = &A[(long)(m0 + ar) * lda + ac];
    float4 av = *(const float4*)ap;
    if (AR == 2) {
        const float4 w = *(const float4*)(ap + sAp);
        av.x += w.x; av.y += w.y; av.z += w.z; av.w += w.w;
    }
    float4 bv0 = *(const float4*)&Bm[(long)(br + 0) * ldb + (n0 + bc)];
    float4 bv1 = *(const float4*)&Bm[(long)(br + 8) * ldb + (n0 + bc)];

    for (int k0 = 0; k0 < K; k0 += 16) {
        __syncthreads();
        As[ac + 0][ar] = av.x; As[ac + 1][ar] = av.y;
        As[ac + 2][ar] = av.z; As[ac + 3][ar] = av.w;
        *(float4*)&Bs[br + 0][bc] = bv0;
        *(float4*)&Bs[br + 8][bc] = bv1;
        __syncthreads();
        if (k0 + 16 < K) {   // next-tile loads overlap compute below
            const float* a2 = &A[(long)(m0 + ar) * lda + (k0 + 16 + ac)];
            av = *(const float4*)a2;
            if (AR == 2) {
                const float4 w = *(const float4*)(a2 + sAp);
                av.x += w.x; av.y += w.y; av.z += w.z; av.w += w.w;
            }
            bv0 = *(const float4*)&Bm[(long)(k0 + 16 + br + 0) * ldb + (n0 + bc)];
            bv1 = *(const float4*)&Bm[(long)(k0 + 16 + br + 8) * ldb + (n0 + bc)];
        }
        #pragma unroll
        for (int kk = 0; kk < 16; ++kk) {
            const float4 a = *(const float4*)&As[kk][ty * 4];
            const float4 b = *(const float4*)&Bs[kk][tx * 4];
            const float aa[4] = {a.x, a.y, a.z, a.w};
            const float bb[4] = {b.x, b.y, b.z, b.w};
            #pragma unroll
            for (int im = 0; im < 4; ++im)
                #pragma unroll
                for (int in = 0; in < 4; ++in)
                    acc[im][in] = fmaf(aa[im], bb[in], acc[im][in]);
        }
    }
    #pragma unroll
    for (int im = 0; im < 4; ++im) {
        const int row = m0 + ty * 4 + im;
        float4 v;
        float* vp = &v.x;
        #pragma unroll
        for (int in = 0; in < 4; ++in) {
            float x = acc[im][in];
            if (bias) x += bias[n0 + tx * 4 + in];
            vp[in] = x;
        }
        *(float4*)&C[(long)row * ldc + (n0 + tx * 4)] = v;
    }
}

// ------------- qkv K-split reduce + bias + scatter to q/keysT/v ------------
__global__ __launch_bounds__(256)
void k_qkvreduce(const float* __restrict__ P, const float* __restrict__ bias,
                 float* __restrict__ q, float* __restrict__ kT,
                 float* __restrict__ v)
{
    const int t = blockIdx.x * 256 + threadIdx.x;      // float4 id, 294912 total
    const int row = t / 576;
    const int c4 = (t - row * 576) * 4;
    const float4 p0 = *(const float4*)&P[(long)row * 2304 + c4];
    const float4 p1 = *(const float4*)&P[PSTRIDE + (long)row * 2304 + c4];
    const float4 bb = *(const float4*)&bias[c4];
    const float r[4] = {p0.x + p1.x + bb.x, p0.y + p1.y + bb.y,
                        p0.z + p1.z + bb.z, p0.w + p1.w + bb.w};
    #pragma unroll
    for (int e = 0; e < 4; ++e) {
        const int col = c4 + e;
        const int i = col / 3, s = col - i * 3;
        if (s == 0)      q [(long)row * Ee + i]  = r[e];
        else if (s == 1) kT[(long)i * BN + row]  = r[e];
        else             v [(long)row * Ee + i]  = r[e];
    }
}

// ---------------- Gaussian-mixture logsumexp (R=8, j-split x8) -------------
// block = one i, 512 threads (8 waves). wave = j-group (96 j's), lane = row-
// group (8 rows, stride 64). Coefficient reads are wave-uniform LDS b128
// broadcasts (conflict-free), amortized over 32 evals. Partial sums reduced
// across j-groups via padded LDS (stride 9 -> 2-way banks = free).
// Mix log-softmax normalizer + 0.5*log(2pi) dropped (uniform shift ->
// softmax-invariant). No max pass (t <= ~8 base-2; overflow impossible).
__global__ __launch_bounds__(512)
void k_mixture(const float* __restrict__ mean, const float* __restrict__ logvar,
               const float* __restrict__ mix, const float* __restrict__ keysT,
               float* __restrict__ kmT)
{
    __shared__ __align__(16) float aS[768], bS[768], cS[768];
    __shared__ float sP[512][9];
    const int i = blockIdx.x;
    const int tid = threadIdx.x;

    for (int j = tid; j < 768; j += 512) {
        const float lv = logvar[i * Ee + j];
        const float mu = mean[i * Ee + j];
        const float istd2 = __builtin_amdgcn_exp2f(-lv * LOG2E);
        aS[j] = -0.5f * LOG2E * istd2;
        bS[j] = LOG2E * mu * istd2;
        cS[j] = fmaf(-0.5f * LOG2E * mu * mu, istd2, LOG2E * (mix[j] - 0.5f * lv));
    }
    __syncthreads();

    const int rg = tid & 63;          // row-group (lane)
    const int jg = tid >> 6;          // j-group (wave)
    float kv[8], k2[8], s[8];
    #pragma unroll
    for (int q = 0; q < 8; ++q) {
        kv[q] = keysT[(long)i * BN + q * 64 + rg];
        k2[q] = kv[q] * kv[q];
        s[q] = 0.f;
    }
    const float4* a4 = (const float4*)(aS + jg * 96);
    const float4* b4 = (const float4*)(bS + jg * 96);
    const float4* c4 = (const float4*)(cS + jg * 96);
    for (int it = 0; it < 24; ++it) {
        const float4 a = a4[it], b = b4[it], c = c4[it];
        #pragma unroll
        for (int q = 0; q < 8; ++q) {
            s[q] += __builtin_amdgcn_exp2f(fmaf(a.x, k2[q], fmaf(b.x, kv[q], c.x)));
            s[q] += __builtin_amdgcn_exp2f(fmaf(a.y, k2[q], fmaf(b.y, kv[q], c.y)));
            s[q] += __builtin_amdgcn_exp2f(fmaf(a.z, k2[q], fmaf(b.z, kv[q], c.z)));
            s[q] += __builtin_amdgcn_exp2f(fmaf(a.w, k2[q], fmaf(b.w, kv[q], c.w)));
        }
    }
    #pragma unroll
    for (int q = 0; q < 8; ++q)
        sP[q * 64 + rg][jg] = s[q];
    __syncthreads();

    const float* rp = sP[tid];
    const float t0 = ((rp[0] + rp[1]) + (rp[2] + rp[3]))
                   + ((rp[4] + rp[5]) + (rp[6] + rp[7]));
    kmT[(long)i * BN + tid] = LN2 * __builtin_amdgcn_logf(t0);
}

// ---------------- row softmax (in-place) with /sqrt(768) folded ------------
__global__ __launch_bounds__(256)
void k_softmax(float* __restrict__ e)
{
    const int row = blockIdx.x * 4 + (threadIdx.x >> 6);
    const int lane = threadIdx.x & 63;
    float4* p = (float4*)(e + (long)row * 256);
    float4 v = p[lane];
    float m = fmaxf(fmaxf(v.x, v.y), fmaxf(v.z, v.w));
    #pragma unroll
    for (int off = 32; off; off >>= 1) m = fmaxf(m, __shfl_xor(m, off, 64));
    v.x = __builtin_amdgcn_exp2f((v.x - m) * LOG2E);
    v.y = __builtin_amdgcn_exp2f((v.y - m) * LOG2E);
    v.z = __builtin_amdgcn_exp2f((v.z - m) * LOG2E);
    v.w = __builtin_amdgcn_exp2f((v.w - m) * LOG2E);
    float s = v.x + v.y + v.z + v.w;
    #pragma unroll
    for (int off = 32; off; off >>= 1) s += __shfl_xor(s, off, 64);
    const float sc = 1.0f / (s * 27.712812921102035f);  // * sqrt(768)
    v.x *= sc; v.y *= sc; v.z *= sc; v.w *= sc;
    p[lane] = v;
}

// ---------------- out = PJP0 + PJP1 + bias ------------
__global__ __launch_bounds__(256)
void k_outbias(const float* __restrict__ PJ, const float* __restrict__ bias,
               float* __restrict__ out)
{
    const int t = blockIdx.x * 256 + threadIdx.x;      // float4 id, 98304 total
    const int row = t / 192;
    const int c4 = (t - row * 192) * 4;
    const float4 p0 = *(const float4*)&PJ[(long)row * 768 + c4];
    const float4 p1 = *(const float4*)&PJ[PART + (long)row * 768 + c4];
    const float4 bb = *(const float4*)&bias[c4];
    float4 v = {p0.x + p1.x + bb.x, p0.y + p1.y + bb.y,
                p0.z + p1.z + bb.z, p0.w + p1.w + bb.w};
    *(float4*)&out[(long)row * 768 + c4] = v;
}

extern "C" void kernel_launch(void* const* d_in, const int* in_sizes, int n_in,
                              void* d_out, int out_size, void* d_ws, size_t ws_size,
                              hipStream_t stream)
{
    (void)in_sizes; (void)n_in; (void)out_size; (void)ws_size;
    const float* x      = (const float*)d_in[0];
    const float* Wqkv   = (const float*)d_in[1];
    const float* bqkv   = (const float*)d_in[2];
    const float* Wproj  = (const float*)d_in[3];
    const float* bproj  = (const float*)d_in[4];
    const float* mean   = (const float*)d_in[5];
    const float* logvar = (const float*)d_in[6];
    const float* mixc   = (const float*)d_in[7];
    float* out = (float*)d_out;
    float* ws = (float*)d_ws;
    float* qc     = ws + QC_OFF;
    float* keysT  = ws + KT_OFF;
    float* vc     = ws + VC_OFF;
    float* P      = ws + P_OFF;
    float* kmT    = ws + KM_OFF;
    float* energy = ws + EN_OFF;
    float* pvp    = ws + PVP_OFF;
    float* pjp    = ws + PJP_OFF;

    // 1a) qkv partials: x @ Wqkv, K split x2 (2304 waves)
    gemm_k<1><<<dim3(16,36,2),128,0,stream>>>(
        x,768,0,0,0, Wqkv,2304,0,0, P,2304,0,0,PSTRIDE,
        nullptr, 384, 1, 2);
    // 1b) reduce + bias + scatter to q / keysT / v
    k_qkvreduce<<<1152,256,0,stream>>>(P, bqkv, qc, keysT, vc);
    // 2) key_mix (transposed output kmT[i][row])
    k_mixture<<<768,512,0,stream>>>(mean, logvar, mixc, keysT, kmT);
    // 3) energy[b,h,q,k] = sum_d q[.,d] * kmT[d][k]  (1536 waves)
    gemm_k<1><<<dim3(8,4,24),128,0,stream>>>(
        qc,768,196608,64,0, kmT,512,256,32768, energy,256,786432,65536,0,
        nullptr, 64, 12, 1);
    // 4) att = softmax(energy)/sqrt(768), in place
    k_softmax<<<1536,256,0,stream>>>(energy);
    // 5) PV partials: att @ v, K split x2 (768 waves) -> pvp over dead q/keysT
    gemm_k<1><<<dim3(8,1,48),128,0,stream>>>(
        energy,256,786432,65536,0, vc,768,196608,64, pvp,768,196608,64,PART,
        nullptr, 128, 12, 2);
    // 6) proj partials: (pvp0+pvp1) @ Wproj, K split x2 (768 waves)
    gemm_k<2><<<dim3(16,12,2),128,0,stream>>>(
        pvp,768,0,0,PART, Wproj,768,0,0, pjp,768,0,0,PART,
        nullptr, 384, 1, 2);
    // 7) out = pjp0 + pjp1 + bproj
    k_outbias<<<384,256,0,stream>>>(pjp, bproj, out);
}

// Round 8
// 108.085 us; speedup vs baseline: 1.3548x; 1.2160x over previous
//
#include <hip/hip_runtime.h>

#define LOG2E 1.4426950408889634f
#define LN2 0.6931471805599453f

typedef __attribute__((ext_vector_type(8))) short bf16x8;
typedef __attribute__((ext_vector_type(4))) float f32x4;

constexpr int Ee = 768;
constexpr int BN = 512;
// ws layout (floats). Overlays (safe by in-stream ordering):
//   P   (qkv partials 2x1179648) at 1179648 -- dead after k_qkvreduce
//   kmT [768][512]               at 1179648 -- written after P dies
//   PVP (PV partials 2x393216)   at 0       -- over dead q/keysT
//   PJP (proj partials 2x393216) at 1179648 -- over dead kmT
constexpr long QC_OFF = 0;              // q       [512][768]
constexpr long KT_OFF = 393216;         // keysT   [768][512]
constexpr long VC_OFF = 786432;         // v       [512][768]
constexpr long P_OFF  = 1179648;        // qkv partials [2][512][2304]
constexpr long PSTRIDE = 1179648;
constexpr long KM_OFF = 1179648;        // kmT     [768][512]
constexpr long EN_OFF = 1572864;        // energy  [24][256][256]
constexpr long PVP_OFF = 0;             // PV partials [2][512][768]
constexpr long PJP_OFF = 1179648;       // proj partials [2][512][768]
constexpr long PART = 393216;

__device__ __forceinline__ unsigned pk_hi(float x0, float x1) {
    return (__float_as_uint(x0) >> 16) | (__float_as_uint(x1) & 0xFFFF0000u);
}
__device__ __forceinline__ float rhi(float x) {
    return __uint_as_float(__float_as_uint(x) & 0xFFFF0000u);
}

// ------------- bf16 hi/lo split MFMA GEMM, 64x64 tile, BK=32 ---------------
// C[m][n] = sum_k A[m][k]*B[k][n] computed as AhBh + AhBl + AlBh (bf16 MFMA,
// fp32 accum; dropped AlBl <= 2^-16 rel). 256 thr = 4 waves; wave = one 32x32
// quadrant = 2x2 frags of v_mfma_f32_16x16x32_bf16.
// Staging: tid<128 stage B (in-register 4x4 transpose -> BsT[n][k]),
// tid>=128 stage A ([m][k], k-contig). XOR swizzle (row&7)<<4 on 128B rows.
// KS: K-split (partial at C + kp*sCp). AR==2: A elem = A[i] + A[i+sAp].
template<int AR>
__global__ __launch_bounds__(256)
void mfma_gemm(const float* __restrict__ A, int lda, long sAb, long sAh, long sAp,
               const float* __restrict__ Bm, int ldb, long sBb, long sBh,
               float* __restrict__ C, int ldc, long sCb, long sCh, long sCp,
               int K, int Hdiv, int KS)
{
    __shared__ __align__(16) unsigned short sm[4 * 64 * 64]; // Ahi,Alo,Bhi,Blo planes
    char* const smb = (char*)sm;
    const int tid = threadIdx.x;
    const int m0 = blockIdx.x * 64, n0 = blockIdx.y * 64;
    const int kp = blockIdx.z % KS;
    const int zz = blockIdx.z / KS;
    const int zb = zz / Hdiv, zh = zz - zb * Hdiv;
    A  += zb * sAb + zh * sAh + (long)kp * K;
    Bm += zb * sBb + zh * sBh + (long)kp * (long)K * ldb;
    C  += zb * sCb + zh * sCh + (long)kp * sCp;

    const int lane = tid & 63, w = tid >> 6;
    const int wr = w >> 1, wc = w & 1;
    const int fr = lane & 15, fko2 = (lane >> 4) * 16;   // frag row, k-byte off

    const bool isB = tid < 128;
    const int kq = isB ? (tid >> 4) : ((tid - 128) & 7); // k-quad 0..7
    const int nq = tid & 15;                             // B: n-quad
    const int mq = (tid - 128) >> 3;                     // A: m-quad

    auto foff = [](int plane, int row, int cb) {
        return plane * 8192 + row * 128 + (cb ^ ((row & 7) << 4));
    };
    int wo[8];
    if (isB) {
        #pragma unroll
        for (int e = 0; e < 4; ++e) {
            wo[e]     = foff(2, nq * 4 + e, kq * 8);
            wo[e + 4] = foff(3, nq * 4 + e, kq * 8);
        }
    } else {
        #pragma unroll
        for (int r = 0; r < 4; ++r) {
            wo[r]     = foff(0, mq * 4 + r, kq * 8);
            wo[r + 4] = foff(1, mq * 4 + r, kq * 8);
        }
    }
    const int oA0h = foff(0, wr * 32 + fr,      fko2);
    const int oA1h = foff(0, wr * 32 + 16 + fr, fko2);
    const int oA0l = oA0h + 8192, oA1l = oA1h + 8192;
    const int oB0h = foff(2, wc * 32 + fr,      fko2);
    const int oB1h = foff(2, wc * 32 + 16 + fr, fko2);
    const int oB0l = oB0h + 8192, oB1l = oB1h + 8192;

    f32x4 acc00 = {}, acc01 = {}, acc10 = {}, acc11 = {};
    float4 r0, r1, r2, r3;

    auto load_regs = [&](int k0) {
        if (isB) {
            const float* p = &Bm[(long)(k0 + kq * 4) * ldb + n0 + nq * 4];
            r0 = *(const float4*)p; p += ldb;
            r1 = *(const float4*)p; p += ldb;
            r2 = *(const float4*)p; p += ldb;
            r3 = *(const float4*)p;
        } else {
            const float* p = &A[(long)(m0 + mq * 4) * lda + k0 + kq * 4];
            r0 = *(const float4*)p;
            if (AR == 2) { float4 t = *(const float4*)(p + sAp);
                r0.x += t.x; r0.y += t.y; r0.z += t.z; r0.w += t.w; }
            p += lda;
            r1 = *(const float4*)p;
            if (AR == 2) { float4 t = *(const float4*)(p + sAp);
                r1.x += t.x; r1.y += t.y; r1.z += t.z; r1.w += t.w; }
            p += lda;
            r2 = *(const float4*)p;
            if (AR == 2) { float4 t = *(const float4*)(p + sAp);
                r2.x += t.x; r2.y += t.y; r2.z += t.z; r2.w += t.w; }
            p += lda;
            r3 = *(const float4*)p;
            if (AR == 2) { float4 t = *(const float4*)(p + sAp);
                r3.x += t.x; r3.y += t.y; r3.z += t.z; r3.w += t.w; }
        }
    };

    auto cvt_store = [&](const float4& v, int o_hi, int o_lo) {
        uint2 hi; hi.x = pk_hi(v.x, v.y); hi.y = pk_hi(v.z, v.w);
        const float l0 = v.x - rhi(v.x), l1 = v.y - rhi(v.y);
        const float l2 = v.z - rhi(v.z), l3 = v.w - rhi(v.w);
        uint2 lo; lo.x = pk_hi(l0, l1); lo.y = pk_hi(l2, l3);
        *(uint2*)(smb + o_hi) = hi;
        *(uint2*)(smb + o_lo) = lo;
    };

    auto stage = [&]() {
        if (isB) {
            // transpose in regs: column e of the 4 loaded k-rows -> BsT row
            #pragma unroll
            for (int e = 0; e < 4; ++e) {
                float4 col;
                col.x = (&r0.x)[e]; col.y = (&r1.x)[e];
                col.z = (&r2.x)[e]; col.w = (&r3.x)[e];
                cvt_store(col, wo[e], wo[e + 4]);
            }
        } else {
            cvt_store(r0, wo[0], wo[4]);
            cvt_store(r1, wo[1], wo[5]);
            cvt_store(r2, wo[2], wo[6]);
            cvt_store(r3, wo[3], wo[7]);
        }
    };

    load_regs(0);
    for (int k0 = 0; k0 < K; k0 += 32) {
        __syncthreads();
        stage();
        __syncthreads();
        if (k0 + 32 < K) load_regs(k0 + 32);
        const bf16x8 Ah0 = *(const bf16x8*)(smb + oA0h);
        const bf16x8 Ah1 = *(const bf16x8*)(smb + oA1h);
        const bf16x8 Al0 = *(const bf16x8*)(smb + oA0l);
        const bf16x8 Al1 = *(const bf16x8*)(smb + oA1l);
        const bf16x8 Bh0 = *(const bf16x8*)(smb + oB0h);
        const bf16x8 Bh1 = *(const bf16x8*)(smb + oB1h);
        const bf16x8 Bl0 = *(const bf16x8*)(smb + oB0l);
        const bf16x8 Bl1 = *(const bf16x8*)(smb + oB1l);
        acc00 = __builtin_amdgcn_mfma_f32_16x16x32_bf16(Ah0, Bh0, acc00, 0, 0, 0);
        acc01 = __builtin_amdgcn_mfma_f32_16x16x32_bf16(Ah0, Bh1, acc01, 0, 0, 0);
        acc10 = __builtin_amdgcn_mfma_f32_16x16x32_bf16(Ah1, Bh0, acc10, 0, 0, 0);
        acc11 = __builtin_amdgcn_mfma_f32_16x16x32_bf16(Ah1, Bh1, acc11, 0, 0, 0);
        acc00 = __builtin_amdgcn_mfma_f32_16x16x32_bf16(Ah0, Bl0, acc00, 0, 0, 0);
        acc01 = __builtin_amdgcn_mfma_f32_16x16x32_bf16(Ah0, Bl1, acc01, 0, 0, 0);
        acc10 = __builtin_amdgcn_mfma_f32_16x16x32_bf16(Ah1, Bl0, acc10, 0, 0, 0);
        acc11 = __builtin_amdgcn_mfma_f32_16x16x32_bf16(Ah1, Bl1, acc11, 0, 0, 0);
        acc00 = __builtin_amdgcn_mfma_f32_16x16x32_bf16(Al0, Bh0, acc00, 0, 0, 0);
        acc01 = __builtin_amdgcn_mfma_f32_16x16x32_bf16(Al0, Bh1, acc01, 0, 0, 0);
        acc10 = __builtin_amdgcn_mfma_f32_16x16x32_bf16(Al1, Bh0, acc10, 0, 0, 0);
        acc11 = __builtin_amdgcn_mfma_f32_16x16x32_bf16(Al1, Bh1, acc11, 0, 0, 0);
    }

    // C/D layout (m89-verified): col = lane&15, row = (lane>>4)*4 + reg
    const int rb = m0 + wr * 32 + (lane >> 4) * 4;
    const int cb = n0 + wc * 32 + fr;
    #pragma unroll
    for (int j = 0; j < 4; ++j) C[(long)(rb + j +  0) * ldc + cb +  0] = acc00[j];
    #pragma unroll
    for (int j = 0; j < 4; ++j) C[(long)(rb + j +  0) * ldc + cb + 16] = acc01[j];
    #pragma unroll
    for (int j = 0; j < 4; ++j) C[(long)(rb + j + 16) * ldc + cb +  0] = acc10[j];
    #pragma unroll
    for (int j = 0; j < 4; ++j) C[(long)(rb + j + 16) * ldc + cb + 16] = acc11[j];
}

// ------------- qkv K-split reduce + bias + scatter to q/keysT/v ------------
__global__ __launch_bounds__(256)
void k_qkvreduce(const float* __restrict__ P, const float* __restrict__ bias,
                 float* __restrict__ q, float* __restrict__ kT,
                 float* __restrict__ v)
{
    const int t = blockIdx.x * 256 + threadIdx.x;      // float4 id, 294912 total
    const int row = t / 576;
    const int c4 = (t - row * 576) * 4;
    const float4 p0 = *(const float4*)&P[(long)row * 2304 + c4];
    const float4 p1 = *(const float4*)&P[PSTRIDE + (long)row * 2304 + c4];
    const float4 bb = *(const float4*)&bias[c4];
    const float r[4] = {p0.x + p1.x + bb.x, p0.y + p1.y + bb.y,
                        p0.z + p1.z + bb.z, p0.w + p1.w + bb.w};
    #pragma unroll
    for (int e = 0; e < 4; ++e) {
        const int col = c4 + e;
        const int i = col / 3, s = col - i * 3;
        if (s == 0)      q [(long)row * Ee + i]  = r[e];
        else if (s == 1) kT[(long)i * BN + row]  = r[e];
        else             v [(long)row * Ee + i]  = r[e];
    }
}

// ---------------- Gaussian-mixture logsumexp (R=8, j-split x8) -------------
__global__ __launch_bounds__(512)
void k_mixture(const float* __restrict__ mean, const float* __restrict__ logvar,
               const float* __restrict__ mix, const float* __restrict__ keysT,
               float* __restrict__ kmT)
{
    __shared__ __align__(16) float aS[768], bS[768], cS[768];
    __shared__ float sP[512][9];
    const int i = blockIdx.x;
    const int tid = threadIdx.x;

    for (int j = tid; j < 768; j += 512) {
        const float lv = logvar[i * Ee + j];
        const float mu = mean[i * Ee + j];
        const float istd2 = __builtin_amdgcn_exp2f(-lv * LOG2E);
        aS[j] = -0.5f * LOG2E * istd2;
        bS[j] = LOG2E * mu * istd2;
        cS[j] = fmaf(-0.5f * LOG2E * mu * mu, istd2, LOG2E * (mix[j] - 0.5f * lv));
    }
    __syncthreads();

    const int rg = tid & 63;
    const int jg = tid >> 6;
    float kv[8], k2[8], s[8];
    #pragma unroll
    for (int q = 0; q < 8; ++q) {
        kv[q] = keysT[(long)i * BN + q * 64 + rg];
        k2[q] = kv[q] * kv[q];
        s[q] = 0.f;
    }
    const float4* a4 = (const float4*)(aS + jg * 96);
    const float4* b4 = (const float4*)(bS + jg * 96);
    const float4* c4 = (const float4*)(cS + jg * 96);
    for (int it = 0; it < 24; ++it) {
        const float4 a = a4[it], b = b4[it], c = c4[it];
        #pragma unroll
        for (int q = 0; q < 8; ++q) {
            s[q] += __builtin_amdgcn_exp2f(fmaf(a.x, k2[q], fmaf(b.x, kv[q], c.x)));
            s[q] += __builtin_amdgcn_exp2f(fmaf(a.y, k2[q], fmaf(b.y, kv[q], c.y)));
            s[q] += __builtin_amdgcn_exp2f(fmaf(a.z, k2[q], fmaf(b.z, kv[q], c.z)));
            s[q] += __builtin_amdgcn_exp2f(fmaf(a.w, k2[q], fmaf(b.w, kv[q], c.w)));
        }
    }
    #pragma unroll
    for (int q = 0; q < 8; ++q)
        sP[q * 64 + rg][jg] = s[q];
    __syncthreads();

    const float* rp = sP[tid];
    const float t0 = ((rp[0] + rp[1]) + (rp[2] + rp[3]))
                   + ((rp[4] + rp[5]) + (rp[6] + rp[7]));
    kmT[(long)i * BN + tid] = LN2 * __builtin_amdgcn_logf(t0);
}

// ---------------- row softmax (in-place) with /sqrt(768) folded ------------
__global__ __launch_bounds__(256)
void k_softmax(float* __restrict__ e)
{
    const int row = blockIdx.x * 4 + (threadIdx.x >> 6);
    const int lane = threadIdx.x & 63;
    float4* p = (float4*)(e + (long)row * 256);
    float4 v = p[lane];
    float m = fmaxf(fmaxf(v.x, v.y), fmaxf(v.z, v.w));
    #pragma unroll
    for (int off = 32; off; off >>= 1) m = fmaxf(m, __shfl_xor(m, off, 64));
    v.x = __builtin_amdgcn_exp2f((v.x - m) * LOG2E);
    v.y = __builtin_amdgcn_exp2f((v.y - m) * LOG2E);
    v.z = __builtin_amdgcn_exp2f((v.z - m) * LOG2E);
    v.w = __builtin_amdgcn_exp2f((v.w - m) * LOG2E);
    float s = v.x + v.y + v.z + v.w;
    #pragma unroll
    for (int off = 32; off; off >>= 1) s += __shfl_xor(s, off, 64);
    const float sc = 1.0f / (s * 27.712812921102035f);  // * sqrt(768)
    v.x *= sc; v.y *= sc; v.z *= sc; v.w *= sc;
    p[lane] = v;
}

// ---------------- out = PJP0 + PJP1 + bias ------------
__global__ __launch_bounds__(256)
void k_outbias(const float* __restrict__ PJ, const float* __restrict__ bias,
               float* __restrict__ out)
{
    const int t = blockIdx.x * 256 + threadIdx.x;      // float4 id, 98304 total
    const int row = t / 192;
    const int c4 = (t - row * 192) * 4;
    const float4 p0 = *(const float4*)&PJ[(long)row * 768 + c4];
    const float4 p1 = *(const float4*)&PJ[PART + (long)row * 768 + c4];
    const float4 bb = *(const float4*)&bias[c4];
    float4 v = {p0.x + p1.x + bb.x, p0.y + p1.y + bb.y,
                p0.z + p1.z + bb.z, p0.w + p1.w + bb.w};
    *(float4*)&out[(long)row * 768 + c4] = v;
}

extern "C" void kernel_launch(void* const* d_in, const int* in_sizes, int n_in,
                              void* d_out, int out_size, void* d_ws, size_t ws_size,
                              hipStream_t stream)
{
    (void)in_sizes; (void)n_in; (void)out_size; (void)ws_size;
    const float* x      = (const float*)d_in[0];
    const float* Wqkv   = (const float*)d_in[1];
    const float* bqkv   = (const float*)d_in[2];
    const float* Wproj  = (const float*)d_in[3];
    const float* bproj  = (const float*)d_in[4];
    const float* mean   = (const float*)d_in[5];
    const float* logvar = (const float*)d_in[6];
    const float* mixc   = (const float*)d_in[7];
    float* out = (float*)d_out;
    float* ws = (float*)d_ws;
    float* qc     = ws + QC_OFF;
    float* keysT  = ws + KT_OFF;
    float* vc     = ws + VC_OFF;
    float* P      = ws + P_OFF;
    float* kmT    = ws + KM_OFF;
    float* energy = ws + EN_OFF;
    float* pvp    = ws + PVP_OFF;
    float* pjp    = ws + PJP_OFF;

    // 1a) qkv partials: x @ Wqkv, K split x2
    mfma_gemm<1><<<dim3(8,36,2),256,0,stream>>>(
        x,768,0,0,0, Wqkv,2304,0,0, P,2304,0,0,PSTRIDE, 384, 1, 2);
    // 1b) reduce + bias + scatter to q / keysT / v
    k_qkvreduce<<<1152,256,0,stream>>>(P, bqkv, qc, keysT, vc);
    // 2) key_mix (transposed output kmT[i][row])
    k_mixture<<<768,512,0,stream>>>(mean, logvar, mixc, keysT, kmT);
    // 3) energy[b,h,q,k] = sum_d q[.,d] * kmT[d][k]
    mfma_gemm<1><<<dim3(4,4,24),256,0,stream>>>(
        qc,768,196608,64,0, kmT,512,256,32768, energy,256,786432,65536,0, 64, 12, 1);
    // 4) att = softmax(energy)/sqrt(768), in place
    k_softmax<<<1536,256,0,stream>>>(energy);
    // 5) PV partials: att @ v, K split x2 -> pvp (over dead q/keysT)
    mfma_gemm<1><<<dim3(4,1,48),256,0,stream>>>(
        energy,256,786432,65536,0, vc,768,196608,64, pvp,768,196608,64,PART, 128, 12, 2);
    // 6) proj partials: (pvp0+pvp1) @ Wproj, K split x2
    mfma_gemm<2><<<dim3(8,12,2),256,0,stream>>>(
        pvp,768,0,0,PART, Wproj,768,0,0, pjp,768,0,0,PART, 384, 1, 2);
    // 7) out = pjp0 + pjp1 + bproj
    k_outbias<<<384,256,0,stream>>>(pjp, bproj, out);
}